// Round 7
// baseline (611.103 us; speedup 1.0000x reference)
//
#include <hip/hip_runtime.h>
#include <hip/hip_bf16.h>
#include <stdint.h>

#define B_SZ 16384
#define K_SZ 5
#define H_SZ 512
#define E_SZ 512
#define MSZ (512 * 512)   // one 512x512 matrix

typedef _Float16 f16;
typedef _Float16 f16x8 __attribute__((ext_vector_type(8)));
typedef float    f32x4 __attribute__((ext_vector_type(4)));

// ---------------------------------------------------------------------------
__device__ __forceinline__ void gload_lds16(const void* g, void* l) {
  __builtin_amdgcn_global_load_lds(
      (const __attribute__((address_space(1))) unsigned int*)g,
      (__attribute__((address_space(3))) unsigned int*)l, 16, 0, 0);
}

__device__ __forceinline__ float fast_tanh(float x) {
  float e = __expf(-2.f * fabsf(x));
  float r = (1.f - e) / (1.f + e);
  return copysignf(r, x);
}

__device__ __forceinline__ void cvt8(const float* src, f16* dst) {
  float4 a = *(const float4*)src;
  float4 b = *(const float4*)(src + 4);
  union { f16 h[8]; uint4 u; } u;
  u.h[0] = (f16)a.x; u.h[1] = (f16)a.y; u.h[2] = (f16)a.z; u.h[3] = (f16)a.w;
  u.h[4] = (f16)b.x; u.h[5] = (f16)b.y; u.h[6] = (f16)b.z; u.h[7] = (f16)b.w;
  *(uint4*)dst = u.u;
}

// ---------------------------------------------------------------------------
// prep_all: Wa->f16 (Wbig slot 0), Ua->f16, Wa^T->f16, query->f16,
// topics->f16, zero bar. Grid = 25088 blocks of 256.
__global__ __launch_bounds__(256)
void prep_all(const float* __restrict__ Wa, const float* __restrict__ Ua,
              const float* __restrict__ query, const float* __restrict__ topics,
              f16* __restrict__ Wbig0, f16* __restrict__ Ua_h,
              f16* __restrict__ WaT, f16* __restrict__ q0h,
              f16* __restrict__ topics_h, unsigned* __restrict__ bar) {
  const int t = threadIdx.x;
  const int bb = blockIdx.x;
  if (bb == 0 && t == 0) *bar = 0u;
  if (bb < 128) {
    size_t o = ((size_t)bb * 256 + t) * 8;
    cvt8(Wa + o, Wbig0 + o);
  } else if (bb < 256) {
    size_t o = ((size_t)(bb - 128) * 256 + t) * 8;
    cvt8(Ua + o, Ua_h + o);
  } else if (bb < 512) {               // transpose Wa -> WaT (f16)
    __shared__ float tile[32][33];
    int blk = bb - 256;
    int bx = blk & 15, by = blk >> 4;
    int tx = t & 31, ty = t >> 5;
    #pragma unroll
    for (int i = 0; i < 32; i += 8)
      tile[ty + i][tx] = Wa[(size_t)(by * 32 + ty + i) * 512 + bx * 32 + tx];
    __syncthreads();
    #pragma unroll
    for (int i = 0; i < 32; i += 8)
      WaT[(size_t)(bx * 32 + ty + i) * 512 + by * 32 + tx] =
          (f16)tile[tx][ty + i];
  } else if (bb < 4608) {              // query (4096 blocks)
    size_t o = ((size_t)(bb - 512) * 256 + t) * 8;
    cvt8(query + o, q0h + o);
  } else {                             // topics (20480 blocks)
    size_t o = ((size_t)(bb - 4608) * 256 + t) * 8;
    cvt8(topics + o, topics_h + o);
  }
}

// ---------------------------------------------------------------------------
// Device-scope barrier (counter zeroed by prep_all).
__device__ __forceinline__ void gbar(unsigned* cnt, unsigned target) {
  __syncthreads();
  if (threadIdx.x == 0) {
    __threadfence();
    __hip_atomic_fetch_add(cnt, 1u, __ATOMIC_ACQ_REL, __HIP_MEMORY_SCOPE_AGENT);
    while (__hip_atomic_load(cnt, __ATOMIC_ACQUIRE,
                             __HIP_MEMORY_SCOPE_AGENT) < target)
      __builtin_amdgcn_s_sleep(2);
    __threadfence();
  }
  __syncthreads();
}

// ---------------------------------------------------------------------------
// Wa powers via split-K persistent kernel, 256 blocks (co-resident: 16 KB LDS
// -> >=10 blocks/CU capacity). Dependency depth 3:
//  L1: Wa2 = Wa*Wa, W2T = (Wa2)^T     (2 GEMMs x 128 blocks)
//  L2: Wa3 = Wa2*Wa, Wa4 = Wa2*Wa2    (2 GEMMs x 128 blocks)
//  L3: Wa5 = Wa4*Wa                   (1 GEMM x 128 blocks)
// Each GEMM: Y[m,n] = sum_k A[m,k]*W[n,k]; 16 tiles of 128x128 x 8 K-slices
// of 64; f32 partials -> reduce to f16.
__global__ __launch_bounds__(256)
void power_split(f16* __restrict__ Wbig, const f16* __restrict__ WaT,
                 f16* __restrict__ W2T, float* __restrict__ part,
                 unsigned* __restrict__ bar) {
  __shared__ f16 As[128 * 32];
  __shared__ f16 Bs[128 * 32];
  const int t = threadIdx.x, l = t & 63, wid = t >> 6;
  const int wm = wid >> 1, wn = wid & 1;
  const int lrow = l & 15, lk = (l >> 4) * 8;
  const int bid = blockIdx.x;           // 256
  float* p0 = part;
  float* p1 = part + (size_t)8 * MSZ;

  auto spk = [&](const f16* A, const f16* W, float* P, int blk) {
    const int tile = blk >> 3, ks = blk & 7;
    const int m0 = (tile >> 2) * 128, n0 = (tile & 3) * 128;
    f32x4 acc[4][4] = {};
    for (int ki = 0; ki < 2; ++ki) {
      const int k0 = ks * 64 + ki * 32;
      #pragma unroll
      for (int p = 0; p < 2; ++p) {
        int c = p * 256 + t, row = c >> 2, seg = c & 3;
        gload_lds16(W + (size_t)(n0 + row) * 512 + k0 + seg * 8,
                    (char*)Bs + c * 16);
        gload_lds16(A + (size_t)(m0 + row) * 512 + k0 + seg * 8,
                    (char*)As + c * 16);
      }
      __syncthreads();
      f16x8 af[4], bf[4];
      #pragma unroll
      for (int mi = 0; mi < 4; ++mi)
        af[mi] = *(const f16x8*)(As + (wm * 64 + mi * 16 + lrow) * 32 + lk);
      #pragma unroll
      for (int ni = 0; ni < 4; ++ni)
        bf[ni] = *(const f16x8*)(Bs + (wn * 64 + ni * 16 + lrow) * 32 + lk);
      #pragma unroll
      for (int mi = 0; mi < 4; ++mi)
        #pragma unroll
        for (int ni = 0; ni < 4; ++ni)
          acc[mi][ni] = __builtin_amdgcn_mfma_f32_16x16x32_f16(
              af[mi], bf[ni], acc[mi][ni], 0, 0, 0);
      __syncthreads();
    }
    float* Ps = P + (size_t)ks * MSZ;
    #pragma unroll
    for (int mi = 0; mi < 4; ++mi)
      #pragma unroll
      for (int j = 0; j < 4; ++j) {
        int row = m0 + wm * 64 + mi * 16 + ((l >> 4) << 2) + j;
        #pragma unroll
        for (int ni = 0; ni < 4; ++ni)
          Ps[(size_t)row * 512 + n0 + wn * 64 + ni * 16 + lrow] =
              acc[mi][ni][j];
      }
  };
  auto reduceg = [&](const float* P, f16* D, int blk) {
    const int base = (blk * 256 + t) * 8;
    float s[8] = {};
    #pragma unroll
    for (int sl = 0; sl < 8; ++sl) {
      const float* q = P + (size_t)sl * MSZ + base;
      float4 a = *(const float4*)q;
      float4 b = *(const float4*)(q + 4);
      s[0] += a.x; s[1] += a.y; s[2] += a.z; s[3] += a.w;
      s[4] += b.x; s[5] += b.y; s[6] += b.z; s[7] += b.w;
    }
    union { f16 h[8]; uint4 u; } cv;
    #pragma unroll
    for (int j = 0; j < 8; ++j) cv.h[j] = (f16)s[j];
    *(uint4*)(D + base) = cv.u;
  };

  f16* Wa1 = Wbig;
  f16* Wa2 = Wbig + MSZ;
  f16* Wa3 = Wbig + 2 * (size_t)MSZ;
  f16* Wa4 = Wbig + 3 * (size_t)MSZ;
  f16* Wa5 = Wbig + 4 * (size_t)MSZ;
  unsigned tg = 0;

  // L1: Wa2 = A=Wa1,W=WaT ; W2T[m,n]=sum Wa[k,m]Wa[n,k] = A=WaT,W=Wa1
  if (bid < 128) spk(Wa1, WaT, p0, bid);
  else           spk(WaT, Wa1, p1, bid - 128);
  gbar(bar, tg += 256);
  if (bid < 128) reduceg(p0, Wa2, bid);
  else           reduceg(p1, W2T, bid - 128);
  gbar(bar, tg += 256);
  // L2: Wa3 = Wa2*Wa ; Wa4 = Wa2*Wa2 (W=W2T)
  if (bid < 128) spk(Wa2, WaT, p0, bid);
  else           spk(Wa2, W2T, p1, bid - 128);
  gbar(bar, tg += 256);
  if (bid < 128) reduceg(p0, Wa3, bid);
  else           reduceg(p1, Wa4, bid - 128);
  gbar(bar, tg += 256);
  // L3: Wa5 = Wa4*Wa
  if (bid < 128) spk(Wa4, WaT, p0, bid);
  gbar(bar, tg += 256);
  if (bid < 128) reduceg(p0, Wa5, bid);
}

// ---------------------------------------------------------------------------
// Fused: X[b,k,h] = sum_e topics[b,k,e]*Ua[h,e] + sum_c q0[b,c]*Wa^(k+1)[h,c]
// epilogue: partials[nt*2+wn][k][b] = sum over block's 128 h of va[h]*tanh(X).
// R4 single-buffer 2-barrier structure; both phases pure global_load_lds.
__global__ __launch_bounds__(256)
void fused_score_gemm(const f16* __restrict__ topics_h,
                      const f16* __restrict__ q0h,
                      const f16* __restrict__ Ua_h,
                      const f16* __restrict__ Wbig,
                      const float* __restrict__ va_w,
                      float* __restrict__ partials) {
  __shared__ f16 As[128 * 32];
  __shared__ f16 Bs[128 * 32];
  const int t = threadIdx.x;
  const int l = t & 63, wid = t >> 6;
  const int wm = wid >> 1, wn = wid & 1;
  int bid = blockIdx.x;
  const int nwg = gridDim.x;               // 2560, %8==0
  bid = (bid & 7) * (nwg >> 3) + (bid >> 3);
  const int kq = bid >> 9;
  const int rem = bid & 511;
  const int mt = rem >> 2, nt = rem & 3;   // consecutive bids share mt -> L2
  const size_t m0 = (size_t)mt * 128;
  const int n0 = nt * 128;
  const int lrow = l & 15;
  const int lk = (l >> 4) * 8;
  const f16* Pk = Wbig + (size_t)kq * MSZ;

  // staging bases: chunk c = p*256+t -> row = p*64 + (t>>2), seg = t&3
  const int srow = t >> 2, sseg = (t & 3) * 8;
  const f16* tA1 = topics_h + ((m0 + srow) * K_SZ + kq) * (size_t)E_SZ + sseg;
  const f16* tB1 = Ua_h + (size_t)(n0 + srow) * 512 + sseg;
  const f16* tA2 = q0h + (m0 + srow) * (size_t)H_SZ + sseg;
  const f16* tB2 = Pk + (size_t)(n0 + srow) * 512 + sseg;

  f32x4 acc[4][4] = {};

  auto compute = [&]() {
    f16x8 af[4], bf[4];
    #pragma unroll
    for (int mi = 0; mi < 4; ++mi)
      af[mi] = *(const f16x8*)(As + (wm * 64 + mi * 16 + lrow) * 32 + lk);
    #pragma unroll
    for (int ni = 0; ni < 4; ++ni)
      bf[ni] = *(const f16x8*)(Bs + (wn * 64 + ni * 16 + lrow) * 32 + lk);
    #pragma unroll
    for (int mi = 0; mi < 4; ++mi)
      #pragma unroll
      for (int ni = 0; ni < 4; ++ni)
        acc[mi][ni] = __builtin_amdgcn_mfma_f32_16x16x32_f16(
            af[mi], bf[ni], acc[mi][ni], 0, 0, 0);
  };

  // phase 1: topics x Ua
  for (int k0 = 0; k0 < 512; k0 += 32) {
    #pragma unroll
    for (int p = 0; p < 2; ++p) {
      gload_lds16(tB1 + (size_t)p * 64 * 512 + k0,
                  (char*)Bs + (p * 256 + t) * 16);
      gload_lds16(tA1 + (size_t)p * 64 * (K_SZ * E_SZ) + k0,
                  (char*)As + (p * 256 + t) * 16);
    }
    __syncthreads();
    compute();
    __syncthreads();
  }
  // phase 2: q0 x Wa^(kq+1)
  for (int k0 = 0; k0 < 512; k0 += 32) {
    #pragma unroll
    for (int p = 0; p < 2; ++p) {
      gload_lds16(tB2 + (size_t)p * 64 * 512 + k0,
                  (char*)Bs + (p * 256 + t) * 16);
      gload_lds16(tA2 + (size_t)p * 64 * H_SZ + k0,
                  (char*)As + (p * 256 + t) * 16);
    }
    __syncthreads();
    compute();
    __syncthreads();
  }

  // epilogue: partial score over this block's 128 h-cols
  const int colbase = n0 + wn * 64 + lrow;
  float va4[4];
  #pragma unroll
  for (int ni = 0; ni < 4; ++ni) va4[ni] = va_w[colbase + ni * 16];

  #pragma unroll
  for (int mi = 0; mi < 4; ++mi) {
    #pragma unroll
    for (int j = 0; j < 4; ++j) {
      float s = 0.f;
      #pragma unroll
      for (int ni = 0; ni < 4; ++ni)
        s += va4[ni] * fast_tanh(acc[mi][ni][j]);
      #pragma unroll
      for (int m = 1; m < 16; m <<= 1) s += __shfl_xor(s, m);
      if (lrow == 0) {
        int row = (int)m0 + wm * 64 + mi * 16 + ((l >> 4) << 2) + j;
        partials[(size_t)(nt * 2 + wn) * (K_SZ * B_SZ) + kq * B_SZ + row] = s;
      }
    }
  }
}

// ---------------------------------------------------------------------------
// scores (8 partial slices) -> softmax -> mt (f16 topics). One wave per row.
__global__ __launch_bounds__(256)
void finalize2(const float* __restrict__ partials,
               const f16* __restrict__ topics_h, const float* __restrict__ cov,
               const float* __restrict__ va_b, float* __restrict__ out) {
  const int wid = threadIdx.x >> 6, l = threadIdx.x & 63;
  const size_t b = (size_t)blockIdx.x * 4 + wid;
  const float vb = va_b[0];

  float s[K_SZ];
  #pragma unroll
  for (int k = 0; k < K_SZ; ++k) {
    float raw = 0.f;
    #pragma unroll
    for (int sl = 0; sl < 8; ++sl)
      raw += partials[(size_t)sl * (K_SZ * B_SZ) + k * B_SZ + b];
    s[k] = (raw + vb) * cov[b * K_SZ + k];
  }

  float m = s[0];
  #pragma unroll
  for (int k = 1; k < K_SZ; ++k) m = fmaxf(m, s[k]);
  float a[K_SZ], d = 0.f;
  #pragma unroll
  for (int k = 0; k < K_SZ; ++k) { a[k] = __expf(s[k] - m); d += a[k]; }
  float inv = 1.f / d;
  #pragma unroll
  for (int k = 0; k < K_SZ; ++k) a[k] *= inv;

  float accv[8] = {};
  #pragma unroll
  for (int k = 0; k < K_SZ; ++k) {
    f16x8 tv = *(const f16x8*)(topics_h + (b * K_SZ + k) * E_SZ + l * 8);
    #pragma unroll
    for (int j = 0; j < 8; ++j) accv[j] += a[k] * (float)tv[j];
  }
  float* mo = out + b * E_SZ + l * 8;
  *(float4*)mo       = make_float4(accv[0], accv[1], accv[2], accv[3]);
  *(float4*)(mo + 4) = make_float4(accv[4], accv[5], accv[6], accv[7]);
  if (l < K_SZ) {
    float av = (l == 0) ? a[0] : (l == 1) ? a[1] : (l == 2) ? a[2]
               : (l == 3) ? a[3] : a[4];
    out[(size_t)B_SZ * E_SZ + b * K_SZ + l] = av;
  }
}

// ---------------------------------------------------------------------------
extern "C" void kernel_launch(void* const* d_in, const int* in_sizes, int n_in,
                              void* d_out, int out_size, void* d_ws, size_t ws_size,
                              hipStream_t stream) {
  const float* query  = (const float*)d_in[0];
  const float* topics = (const float*)d_in[1];
  const float* cov    = (const float*)d_in[2];
  const float* Ua     = (const float*)d_in[3];
  const float* Wa     = (const float*)d_in[4];
  const float* va_w   = (const float*)d_in[5];
  const float* va_b   = (const float*)d_in[6];
  float* out = (float*)d_out;

  char* ws = (char*)d_ws;
  size_t off = 0;
  auto alloc = [&](size_t bytes) -> char* {
    char* p = ws + off;
    off += (bytes + 255) & ~(size_t)255;
    return p;
  };
  f16* topics_h = (f16*)alloc((size_t)B_SZ * K_SZ * E_SZ * 2);   // 83.9 MB
  f16* q0h      = (f16*)alloc((size_t)B_SZ * H_SZ * 2);          // 16.8 MB
  f16* Ua_h     = (f16*)alloc((size_t)MSZ * 2);                  // 0.5 MB
  f16* WaT      = (f16*)alloc((size_t)MSZ * 2);                  // 0.5 MB
  f16* Wbig     = (f16*)alloc((size_t)K_SZ * MSZ * 2);           // 2.6 MB
  f16* W2T      = (f16*)alloc((size_t)MSZ * 2);                  // 0.5 MB
  float* part   = (float*)alloc((size_t)16 * MSZ * 4);           // 16.8 MB
  float* partials = (float*)alloc((size_t)8 * K_SZ * B_SZ * 4);  // 2.6 MB
  unsigned* bar = (unsigned*)alloc(256);

  prep_all<<<25088, 256, 0, stream>>>(Wa, Ua, query, topics, Wbig, Ua_h, WaT,
                                      q0h, topics_h, bar);
  power_split<<<256, 256, 0, stream>>>(Wbig, WaT, W2T, part, bar);
  fused_score_gemm<<<K_SZ * (B_SZ / 128) * (H_SZ / 128), 256, 0, stream>>>(
      topics_h, q0h, Ua_h, Wbig, va_w, partials);
  finalize2<<<B_SZ / 4, 256, 0, stream>>>(partials, topics_h, cov, va_b, out);
}